// Round 1
// baseline (897.249 us; speedup 1.0000x reference)
//
#include <hip/hip_runtime.h>

// ESSAttn: b=8, C=64, H=W=256 (N=65536), fp32 in/out.
// out[b,n,d] = x_col(n) @ w_vln[d,:] + bias2[d] + w_row[n] * sum_c q2[n,c]*kvw[b][c][d]
//   where kvw[c][d] = (1/(256*knorm_c)) * sum_e kvu[c][e]*w_ln[d][e],
//         kvu[c][e] = sum_n k2t[n,c]*v[n,e],  knorm_c = max(sqrt(sum_n k2t^2),1e-12)
//         k2t = (k-mean)^2/(k2s+1e-7), q2 = (q-mean)^2, w_row folds q2 normalizations.
#define CC 64
#define NN 65536
#define BB 8
#define TN 64
#define G1 96
#define WT_STRIDE 132  // padded [c][128] weight tile stride: bank = (4c+dcol)%32

// ---------------- K0: w_vln[d][c] = sum_e w_ln[d][e]*w_v[e][c]; bias2[d] = w_ln[d,:]@b_v + b_ln[d]
__global__ void k0_prep(const float* __restrict__ w_qkv, const float* __restrict__ b_qkv,
                        const float* __restrict__ w_ln, const float* __restrict__ b_ln,
                        float* __restrict__ wvln, float* __restrict__ bias2) {
    int idx = blockIdx.x * 256 + threadIdx.x;
    if (idx < 4096) {
        int d = idx >> 6, c = idx & 63;
        float s = 0.f;
        #pragma unroll 8
        for (int e = 0; e < 64; ++e)
            s += w_ln[d * 64 + e] * w_qkv[(128 + e) * 64 + c];
        wvln[idx] = s;
    }
    if (blockIdx.x == 0 && threadIdx.x < 64) {
        int d = threadIdx.x;
        float s = b_ln[d];
        #pragma unroll 8
        for (int e = 0; e < 64; ++e)
            s += w_ln[d * 64 + e] * b_qkv[128 + e];
        bias2[d] = s;
    }
}

// ---------------- K1: per (b, g) block: loop tiles of 64 n; compute k,v; stats; accumulate
// kvu partial [64c][64d] in regs, ksq partial [64c] in LDS; flush to per-block slices.
__global__ __launch_bounds__(256, 3) void k1_kv(const float* __restrict__ x,
        const float* __restrict__ w_qkv, const float* __restrict__ b_qkv,
        float* __restrict__ kvu_part, float* __restrict__ ksq_part) {
    __shared__ float sm[WT_STRIDE * 64 + 4096 + 64];  // wt | xs | ksq ; wt region reused as kt_t+vt
    float* wt = sm;                       // [c][dcol] stride WT_STRIDE during GEMM
    float* xs = sm + WT_STRIDE * 64;      // [c][j] stride 64
    float* ksq_s = sm + WT_STRIDE * 64 + 4096;
    float* kt_t = sm;                     // after GEMM: [c][j] stride 64 (k2t)
    float* vt = sm + 4096;                // after GEMM: [j][d] stride 64

    const int tid = threadIdx.x;
    const int b = blockIdx.y, g = blockIdx.x;
    const float* xb = x + (size_t)b * CC * NN;
    const float* wsrc = w_qkv + 64 * 64;  // rows 64..191 = w_k|w_v
    const int ng = tid & 15, dg = tid >> 4;
    const int jn = ng * 4;                // n offset in tile
    const int d0 = dg * 8;                // dcol offset (0..120); <64 => k, >=64 => v
    const int c0 = jn;                    // kvu c-tile
    const int dd0 = dg * 4;               // kvu d-tile

    float binit[8];
    #pragma unroll
    for (int u = 0; u < 8; ++u) binit[u] = b_qkv[64 + d0 + u];

    float acc2[4][4];
    #pragma unroll
    for (int i = 0; i < 4; ++i)
        #pragma unroll
        for (int u = 0; u < 4; ++u) acc2[i][u] = 0.f;
    if (tid < 64) ksq_s[tid] = 0.f;

    for (int t = g; t < NN / TN; t += G1) {
        const int n0 = t * TN;
        // stage x tile [c][j] (coalesced float4)
        #pragma unroll
        for (int l = 0; l < 4; ++l) {
            int idx = tid + l * 256;
            int c = idx >> 4, j4 = (idx & 15) * 4;
            *(float4*)(xs + c * 64 + j4) = *(const float4*)(xb + (size_t)c * NN + n0 + j4);
        }
        // stage weights transposed: wt[c][dcol] = w_qkv[64+dcol][c] (coalesced reads)
        #pragma unroll
        for (int l = 0; l < 32; ++l) {
            int idx = tid + l * 256;
            int c = idx & 63, dcol = idx >> 6;
            wt[c * WT_STRIDE + dcol] = wsrc[dcol * 64 + c];
        }
        __syncthreads();
        // GEMM A: [64 n] x [128 dcol], K=64
        float acc[4][8];
        #pragma unroll
        for (int i = 0; i < 4; ++i)
            #pragma unroll
            for (int u = 0; u < 8; ++u) acc[i][u] = binit[u];
        #pragma unroll 4
        for (int c = 0; c < 64; ++c) {
            float4 xv = *(const float4*)(xs + c * 64 + jn);
            float4 wa = *(const float4*)(wt + c * WT_STRIDE + d0);
            float4 wb = *(const float4*)(wt + c * WT_STRIDE + d0 + 4);
            float xr[4] = {xv.x, xv.y, xv.z, xv.w};
            float wr[8] = {wa.x, wa.y, wa.z, wa.w, wb.x, wb.y, wb.z, wb.w};
            #pragma unroll
            for (int i = 0; i < 4; ++i)
                #pragma unroll
                for (int u = 0; u < 8; ++u)
                    acc[i][u] += xr[i] * wr[u];
        }
        __syncthreads();  // wt & xs consumed
        // scatter: k transposed [c][j]; v natural [j][d]
        if (d0 < 64) {
            #pragma unroll
            for (int u = 0; u < 8; ++u)
                *(float4*)(kt_t + (d0 + u) * 64 + jn) =
                    make_float4(acc[0][u], acc[1][u], acc[2][u], acc[3][u]);
        } else {
            #pragma unroll
            for (int i = 0; i < 4; ++i) {
                *(float4*)(vt + (jn + i) * 64 + (d0 - 64)) =
                    make_float4(acc[i][0], acc[i][1], acc[i][2], acc[i][3]);
                *(float4*)(vt + (jn + i) * 64 + (d0 - 64) + 4) =
                    make_float4(acc[i][4], acc[i][5], acc[i][6], acc[i][7]);
            }
        }
        __syncthreads();
        // stats per n-row j: center, square, scale by 1/(k2s+eps); ksq via staggered LDS atomics
        if (tid < 64) {
            const int j = tid;
            float s1 = 0.f, s2 = 0.f;
            #pragma unroll 8
            for (int c = 0; c < 64; ++c) {
                float k = kt_t[c * 64 + j];
                s1 += k; s2 += k * k;
            }
            float mu = s1 * 0.015625f;
            float k2s = s2 - 64.f * mu * mu;
            float r = 1.f / (k2s + 1e-7f);
            #pragma unroll 4
            for (int s = 0; s < 64; ++s) {
                int c = (j + s) & 63;
                float kc = kt_t[c * 64 + j] - mu;
                float t2 = kc * kc * r;
                kt_t[c * 64 + j] = t2;
                atomicAdd(&ksq_s[c], t2 * t2);
            }
        }
        __syncthreads();
        // kvu: acc2[c0+i][dd0+u] += sum_j k2t[c][j]*v[j][d]
        #pragma unroll 2
        for (int jb = 0; jb < 64; jb += 4) {
            float4 kk[4], vv[4];
            #pragma unroll
            for (int i = 0; i < 4; ++i)
                kk[i] = *(const float4*)(kt_t + (c0 + i) * 64 + jb);
            #pragma unroll
            for (int jj = 0; jj < 4; ++jj)
                vv[jj] = *(const float4*)(vt + (jb + jj) * 64 + dd0);
            #pragma unroll
            for (int i = 0; i < 4; ++i) {
                float kr[4] = {kk[i].x, kk[i].y, kk[i].z, kk[i].w};
                #pragma unroll
                for (int jj = 0; jj < 4; ++jj) {
                    acc2[i][0] += kr[jj] * vv[jj].x;
                    acc2[i][1] += kr[jj] * vv[jj].y;
                    acc2[i][2] += kr[jj] * vv[jj].z;
                    acc2[i][3] += kr[jj] * vv[jj].w;
                }
            }
        }
        __syncthreads();
    }
    // flush per-block partials (deterministic, no global atomics)
    float* kp = kvu_part + (size_t)(b * G1 + g) * 4096;
    #pragma unroll
    for (int i = 0; i < 4; ++i)
        *(float4*)(kp + (c0 + i) * 64 + dd0) =
            make_float4(acc2[i][0], acc2[i][1], acc2[i][2], acc2[i][3]);
    if (tid < 64) ksq_part[(size_t)(b * G1 + g) * 64 + tid] = ksq_s[tid];
}

// ---------------- K2: reduce partials, build kvw[b][c][d] = inv_k[c]*sum_e kvu[c][e]*w_ln[d][e]
__global__ void k2_kvw(const float* __restrict__ kvu_part, const float* __restrict__ ksq_part,
                       const float* __restrict__ w_ln, float* __restrict__ kvw) {
    __shared__ float kvr[8 * 64];
    __shared__ float wln_t[64 * 64];  // [e][d]
    __shared__ float inv_k[8];
    const int tid = threadIdx.x;
    const int cg = blockIdx.x, b = blockIdx.y;
    for (int idx = tid; idx < 4096; idx += 256) {
        int e = idx >> 6, d = idx & 63;
        wln_t[e * 64 + d] = w_ln[d * 64 + e];
    }
    if (tid < 8) {
        int c = cg * 8 + tid;
        float s = 0.f;
        for (int g = 0; g < G1; ++g)
            s += ksq_part[(size_t)(b * G1 + g) * 64 + c];
        float n = fmaxf(sqrtf(s), 1e-12f);
        inv_k[tid] = 1.f / (n * 256.f);  // fold 1/sqrt(N)
    }
    __syncthreads();
    for (int oi = tid; oi < 512; oi += 256) {
        int cl = oi >> 6, e = oi & 63;
        int c = cg * 8 + cl;
        float s = 0.f;
        for (int g = 0; g < G1; ++g)
            s += kvu_part[(size_t)(b * G1 + g) * 4096 + c * 64 + e];
        kvr[cl * 64 + e] = s * inv_k[cl];
    }
    __syncthreads();
    for (int oi = tid; oi < 512; oi += 256) {
        int cl = oi >> 6, d = oi & 63;
        float s = 0.f;
        #pragma unroll 8
        for (int e = 0; e < 64; ++e)
            s += kvr[cl * 64 + e] * wln_t[e * 64 + d];
        kvw[(size_t)b * 4096 + (cg * 8 + cl) * 64 + d] = s;
    }
}

// ---------------- K3: per tile of 64 n: q GEMM + x@w_vln^T; q stats; q2@kvw; store transposed
__global__ __launch_bounds__(256, 3) void k3_out(const float* __restrict__ x,
        const float* __restrict__ w_qkv, const float* __restrict__ b_qkv,
        const float* __restrict__ wvln, const float* __restrict__ bias2,
        const float* __restrict__ kvw, float* __restrict__ out) {
    __shared__ float sm[WT_STRIDE * 64 + 4096 + 64];
    float* wt = sm;                     // [c][dcol]: dcol<64 -> w_q, >=64 -> w_vln
    float* xs = sm + WT_STRIDE * 64;    // [c][j]; reused as qt_t (q2 values)
    float* w_row = sm + WT_STRIDE * 64 + 4096;
    float* qt_t = xs;
    float* ot = sm;                     // after GEMM: [j][d] (x@w_vln^T + bias2)
    float* kvw_s = sm + 4096;           // [c][d]

    const int tid = threadIdx.x;
    const int b = blockIdx.y;
    const int n0 = blockIdx.x * TN;
    const float* xb = x + (size_t)b * CC * NN;
    const int ng = tid & 15, dg = tid >> 4;
    const int jn = ng * 4, d0 = dg * 8;
    const int dd0 = dg * 4;

    #pragma unroll
    for (int l = 0; l < 4; ++l) {
        int idx = tid + l * 256;
        int c = idx >> 4, j4 = (idx & 15) * 4;
        *(float4*)(xs + c * 64 + j4) = *(const float4*)(xb + (size_t)c * NN + n0 + j4);
    }
    #pragma unroll
    for (int l = 0; l < 32; ++l) {
        int idx = tid + l * 256;
        int c = idx & 63, dcol = idx >> 6;
        float wv = (dcol < 64) ? w_qkv[dcol * 64 + c] : wvln[(dcol - 64) * 64 + c];
        wt[c * WT_STRIDE + dcol] = wv;
    }
    __syncthreads();
    float acc[4][8];
    {
        float binit[8];
        #pragma unroll
        for (int u = 0; u < 8; ++u)
            binit[u] = (d0 < 64) ? b_qkv[d0 + u] : bias2[d0 - 64 + u];
        #pragma unroll
        for (int i = 0; i < 4; ++i)
            #pragma unroll
            for (int u = 0; u < 8; ++u) acc[i][u] = binit[u];
    }
    #pragma unroll 4
    for (int c = 0; c < 64; ++c) {
        float4 xv = *(const float4*)(xs + c * 64 + jn);
        float4 wa = *(const float4*)(wt + c * WT_STRIDE + d0);
        float4 wb = *(const float4*)(wt + c * WT_STRIDE + d0 + 4);
        float xr[4] = {xv.x, xv.y, xv.z, xv.w};
        float wr[8] = {wa.x, wa.y, wa.z, wa.w, wb.x, wb.y, wb.z, wb.w};
        #pragma unroll
        for (int i = 0; i < 4; ++i)
            #pragma unroll
            for (int u = 0; u < 8; ++u)
                acc[i][u] += xr[i] * wr[u];
    }
    __syncthreads();  // wt & xs consumed
    if (d0 < 64) {  // q part, transposed [c][j]
        #pragma unroll
        for (int u = 0; u < 8; ++u)
            *(float4*)(qt_t + (d0 + u) * 64 + jn) =
                make_float4(acc[0][u], acc[1][u], acc[2][u], acc[3][u]);
    } else {        // v@w_ln^T part (+bias2), natural [j][d]
        #pragma unroll
        for (int i = 0; i < 4; ++i) {
            *(float4*)(ot + (jn + i) * 64 + (d0 - 64)) =
                make_float4(acc[i][0], acc[i][1], acc[i][2], acc[i][3]);
            *(float4*)(ot + (jn + i) * 64 + (d0 - 64) + 4) =
                make_float4(acc[i][4], acc[i][5], acc[i][6], acc[i][7]);
        }
    }
    // stage kvw for this batch (region distinct from ot)
    for (int idx = tid; idx < 4096; idx += 256)
        kvw_s[idx] = kvw[(size_t)b * 4096 + idx];
    __syncthreads();
    // q stats: center, square; w_row folds /(q2s+eps) and L2-normalize over C
    if (tid < 64) {
        const int j = tid;
        float s1 = 0.f, s2 = 0.f;
        #pragma unroll 8
        for (int c = 0; c < 64; ++c) {
            float q = qt_t[c * 64 + j];
            s1 += q; s2 += q * q;
        }
        float mu = s1 * 0.015625f;
        float q2s = s2 - 64.f * mu * mu;
        float s4 = 0.f;
        #pragma unroll 4
        for (int c = 0; c < 64; ++c) {
            float qc = qt_t[c * 64 + j] - mu;
            float q2 = qc * qc;
            qt_t[c * 64 + j] = q2;
            s4 += q2 * q2;
        }
        float denom = fmaxf(sqrtf(s4), 1e-12f * (q2s + 1e-7f));
        w_row[j] = 1.f / denom;
    }
    __syncthreads();
    // GEMM B: accb[j][d] = sum_c q2[c][j] * kvw_s[c][d]
    float accb[4][4];
    #pragma unroll
    for (int i = 0; i < 4; ++i)
        #pragma unroll
        for (int u = 0; u < 4; ++u) accb[i][u] = 0.f;
    #pragma unroll 4
    for (int c = 0; c < 64; ++c) {
        float4 qv = *(const float4*)(qt_t + c * 64 + jn);
        float4 kv4 = *(const float4*)(kvw_s + c * 64 + dd0);
        float qr[4] = {qv.x, qv.y, qv.z, qv.w};
        #pragma unroll
        for (int i = 0; i < 4; ++i) {
            accb[i][0] += qr[i] * kv4.x;
            accb[i][1] += qr[i] * kv4.y;
            accb[i][2] += qr[i] * kv4.z;
            accb[i][3] += qr[i] * kv4.w;
        }
    }
    // epilogue: out[(b*64+d)*N + n] = accb*w_row[j] + ot[j][d]
    float wr4[4];
    float4 ov[4];
    #pragma unroll
    for (int i = 0; i < 4; ++i) {
        wr4[i] = w_row[jn + i];
        ov[i] = *(const float4*)(ot + (jn + i) * 64 + dd0);
    }
    const size_t ob = (size_t)b * CC * NN;
    {
        float4 o0 = make_float4(accb[0][0] * wr4[0] + ov[0].x, accb[1][0] * wr4[1] + ov[1].x,
                                accb[2][0] * wr4[2] + ov[2].x, accb[3][0] * wr4[3] + ov[3].x);
        float4 o1 = make_float4(accb[0][1] * wr4[0] + ov[0].y, accb[1][1] * wr4[1] + ov[1].y,
                                accb[2][1] * wr4[2] + ov[2].y, accb[3][1] * wr4[3] + ov[3].y);
        float4 o2 = make_float4(accb[0][2] * wr4[0] + ov[0].z, accb[1][2] * wr4[1] + ov[1].z,
                                accb[2][2] * wr4[2] + ov[2].z, accb[3][2] * wr4[3] + ov[3].z);
        float4 o3 = make_float4(accb[0][3] * wr4[0] + ov[0].w, accb[1][3] * wr4[1] + ov[1].w,
                                accb[2][3] * wr4[2] + ov[2].w, accb[3][3] * wr4[3] + ov[3].w);
        *(float4*)(out + ob + (size_t)(dd0 + 0) * NN + n0 + jn) = o0;
        *(float4*)(out + ob + (size_t)(dd0 + 1) * NN + n0 + jn) = o1;
        *(float4*)(out + ob + (size_t)(dd0 + 2) * NN + n0 + jn) = o2;
        *(float4*)(out + ob + (size_t)(dd0 + 3) * NN + n0 + jn) = o3;
    }
}

extern "C" void kernel_launch(void* const* d_in, const int* in_sizes, int n_in,
                              void* d_out, int out_size, void* d_ws, size_t ws_size,
                              hipStream_t stream) {
    const float* x     = (const float*)d_in[0];
    const float* w_qkv = (const float*)d_in[1];
    const float* b_qkv = (const float*)d_in[2];
    const float* w_ln  = (const float*)d_in[3];
    const float* b_ln  = (const float*)d_in[4];
    float* out = (float*)d_out;
    float* ws = (float*)d_ws;
    float* kvu_part = ws;                     // 8*96*4096 = 3145728
    float* ksq_part = ws + 3145728;           // 8*96*64   = 49152
    float* kvw      = ws + 3145728 + 49152;   // 8*4096    = 32768
    float* wvln     = ws + 3145728 + 49152 + 32768;           // 4096
    float* bias2    = ws + 3145728 + 49152 + 32768 + 4096;    // 64

    k0_prep<<<dim3(16), dim3(256), 0, stream>>>(w_qkv, b_qkv, w_ln, b_ln, wvln, bias2);
    k1_kv<<<dim3(G1, BB), dim3(256), 0, stream>>>(x, w_qkv, b_qkv, kvu_part, ksq_part);
    k2_kvw<<<dim3(8, BB), dim3(256), 0, stream>>>(kvu_part, ksq_part, w_ln, kvw);
    k3_out<<<dim3(NN / TN, BB), dim3(256), 0, stream>>>(x, w_qkv, b_qkv, wvln, bias2, kvw, out);
}

// Round 2
// 398.759 us; speedup vs baseline: 2.2501x; 2.2501x over previous
//
#include <hip/hip_runtime.h>

// ESSAttn bf16-MFMA version. b=8, C=64, H=W=256 (N=65536), fp32 in/out.
// Math (exact refactor of reference):
//   out[b,n,d] = x_col(n)@wvln[d,:] + bias2[d] + w_row[n] * sum_c q2[n,c]*kvw[b][c][d]
//   kvw[c][d]  = inv_k[c] * sum_e kvu[c][e]*w_ln[d][e],  inv_k = 1/(256*max(sqrt(ksq_c),1e-12))
//   kvu[c][e]  = sum_n k2t[n,c]*v[n,e],  ksq_c = sum_n k2t^2
//   k2t = (k-mean_c(k))^2/(k2s+1e-7),  q2 = (q-mean)^2, w_row folds q2 normalizations.
// All GEMMs via v_mfma_f32_16x16x32_bf16 (A[m=lane&15][k=quad*8+j], B[n=lane&15][k],
// D col=lane&15 row=quad*4+reg). Accumulation fp32; only MFMA inputs are bf16.

typedef unsigned short u16;
typedef unsigned int u32;
typedef short bf16x8_t __attribute__((ext_vector_type(8)));
typedef float f32x4_t __attribute__((ext_vector_type(4)));

#define NN 65536
#define G1 96
#define STK 68   // bf16 LDS tile stride (elements): 4-way worst-case on b64 frag reads
#define STO 72   // fp32 out-transpose stride

static __device__ __forceinline__ u16 f2bf(float f) {
    union { float f; u32 u; } v; v.f = f;
    u32 r = v.u + 0x7FFFu + ((v.u >> 16) & 1u);
    return (u16)(r >> 16);
}
static __device__ __forceinline__ u32 pack2(float a, float b) {
    return (u32)f2bf(a) | ((u32)f2bf(b) << 16);
}

// ---------------- K0: cast weights to bf16; wvln = w_ln @ w_v; bias2 = w_ln@b_v + b_ln
__global__ void k0_prep(const float* __restrict__ w_qkv, const float* __restrict__ b_qkv,
                        const float* __restrict__ w_ln, const float* __restrict__ b_ln,
                        u16* __restrict__ w_kv_bf, u16* __restrict__ w_q_bf,
                        u16* __restrict__ wvln_bf, float* __restrict__ bias2) {
    int idx = blockIdx.x * 256 + threadIdx.x;
    if (idx < 8192) {                       // rows 64..191 of w_qkv = [w_k | w_v]
        w_kv_bf[idx] = f2bf(w_qkv[4096 + idx]);
    } else if (idx < 12288) {               // rows 0..63 = w_q
        w_q_bf[idx - 8192] = f2bf(w_qkv[idx - 8192]);
    } else if (idx < 16384) {
        int i = idx - 12288; int d = i >> 6, c = i & 63;
        float s = 0.f;
        #pragma unroll 8
        for (int e = 0; e < 64; ++e)
            s += w_ln[d * 64 + e] * w_qkv[(128 + e) * 64 + c];
        wvln_bf[i] = f2bf(s);
    } else if (idx < 16448) {
        int d = idx - 16384;
        float s = b_ln[d];
        #pragma unroll 8
        for (int e = 0; e < 64; ++e)
            s += w_ln[d * 64 + e] * b_qkv[128 + e];
        bias2[d] = s;
    }
}

// ---------------- K1: per (g,b): loop n-tiles of 64; MFMA k|v GEMM; shuffle stats;
// LDS-transpose k2t,v to bf16; MFMA kvu accumulation in AGPRs; flush per-block partials.
__global__ __launch_bounds__(256) void k1_kv(const float* __restrict__ x,
        const u16* __restrict__ w_kv_bf, const float* __restrict__ b_qkv,
        float* __restrict__ kvu_part, float* __restrict__ ksq_part) {
    __shared__ u16 kt[64 * STK];   // k2t^T: [c][n] bf16
    __shared__ u16 vt[64 * STK];   // v^T:   [e][n] bf16
    __shared__ float ksq_red[4][64];
    const int tid = threadIdx.x;
    const int w = tid >> 6, lane = tid & 63, q = lane >> 4, l15 = lane & 15;
    const int b = blockIdx.y, g = blockIdx.x;
    const float* xb = x + (size_t)b * 64 * NN;

    float bias[8];
    #pragma unroll
    for (int t8 = 0; t8 < 8; ++t8) bias[t8] = b_qkv[64 + 16 * t8 + l15];

    f32x4_t accK[4];
    #pragma unroll
    for (int et = 0; et < 4; ++et) accK[et] = (f32x4_t){0.f, 0.f, 0.f, 0.f};
    float ksq_acc[4] = {0.f, 0.f, 0.f, 0.f};

    for (int t = g; t < NN / 64; t += G1) {
        const int n0 = t * 64;
        // ---- GEMM A: D[n][dcol], dcol 0..63 = k, 64..127 = v (K = 64 channels)
        f32x4_t accA[8];
        #pragma unroll
        for (int t8 = 0; t8 < 8; ++t8)
            accA[t8] = (f32x4_t){bias[t8], bias[t8], bias[t8], bias[t8]};
        #pragma unroll
        for (int ks = 0; ks < 2; ++ks) {
            // A-frag: x^T[n][c] via strided global dwords (each element read once)
            const float* xp = xb + (size_t)(ks * 32 + q * 8) * NN + n0 + 16 * w + l15;
            union { u16 u[8]; bf16x8_t v; } af;
            #pragma unroll
            for (int j = 0; j < 8; ++j) af.u[j] = f2bf(xp[(size_t)j * NN]);
            #pragma unroll
            for (int t8 = 0; t8 < 8; ++t8) {
                bf16x8_t bf = *(const bf16x8_t*)(w_kv_bf + (16 * t8 + l15) * 64 + ks * 32 + q * 8);
                accA[t8] = __builtin_amdgcn_mfma_f32_16x16x32_bf16(af.v, bf, accA[t8], 0, 0, 0);
            }
        }
        // ---- k stats per row (row = 4q + r): mean, 1/(k2s+eps) via 16-lane butterflies
        float mu[4], rin[4];
        #pragma unroll
        for (int r = 0; r < 4; ++r) {
            float a0 = accA[0][r], a1 = accA[1][r], a2 = accA[2][r], a3 = accA[3][r];
            float s1 = a0 + a1 + a2 + a3;
            float s2 = a0 * a0 + a1 * a1 + a2 * a2 + a3 * a3;
            #pragma unroll
            for (int m = 1; m <= 8; m <<= 1) {
                s1 += __shfl_xor(s1, m, 64);
                s2 += __shfl_xor(s2, m, 64);
            }
            mu[r] = s1 * 0.015625f;
            rin[r] = 1.f / (s2 - 64.f * mu[r] * mu[r] + 1e-7f);
        }
        // ---- k2t -> kt LDS (bf16), ksq accumulate; v -> vt LDS
        #pragma unroll
        for (int t4 = 0; t4 < 4; ++t4) {
            float t2v[4];
            #pragma unroll
            for (int r = 0; r < 4; ++r) {
                float d = accA[t4][r] - mu[r];
                float t2 = d * d * rin[r];
                t2v[r] = t2;
                ksq_acc[t4] += t2 * t2;
            }
            int base = (16 * t4 + l15) * STK + 16 * w + 4 * q;
            *(u32*)&kt[base] = pack2(t2v[0], t2v[1]);
            *(u32*)&kt[base + 2] = pack2(t2v[2], t2v[3]);
        }
        #pragma unroll
        for (int t4 = 0; t4 < 4; ++t4) {
            int base = (16 * t4 + l15) * STK + 16 * w + 4 * q;
            *(u32*)&vt[base] = pack2(accA[4 + t4][0], accA[4 + t4][1]);
            *(u32*)&vt[base + 2] = pack2(accA[4 + t4][2], accA[4 + t4][3]);
        }
        __syncthreads();
        // ---- kvu: D[c][e] += sum_n k2t[n][c]*v[n][e]; wave w owns c-tile w
        #pragma unroll
        for (int ks2 = 0; ks2 < 2; ++ks2) {
            union { bf16x8_t v; uint2 h[2]; } a2;
            const u16* ap = &kt[(16 * w + l15) * STK + ks2 * 32 + q * 8];
            a2.h[0] = *(const uint2*)ap;
            a2.h[1] = *(const uint2*)(ap + 4);
            #pragma unroll
            for (int et = 0; et < 4; ++et) {
                union { bf16x8_t v; uint2 h[2]; } b2;
                const u16* bp = &vt[(16 * et + l15) * STK + ks2 * 32 + q * 8];
                b2.h[0] = *(const uint2*)bp;
                b2.h[1] = *(const uint2*)(bp + 4);
                accK[et] = __builtin_amdgcn_mfma_f32_16x16x32_bf16(a2.v, b2.v, accK[et], 0, 0, 0);
            }
        }
        __syncthreads();
    }
    // ---- flush partials
    float* kp = kvu_part + (size_t)(b * G1 + g) * 4096;
    #pragma unroll
    for (int et = 0; et < 4; ++et)
        #pragma unroll
        for (int r = 0; r < 4; ++r)
            kp[(16 * w + 4 * q + r) * 64 + 16 * et + l15] = accK[et][r];
    #pragma unroll
    for (int t4 = 0; t4 < 4; ++t4) {
        float v = ksq_acc[t4];
        v += __shfl_xor(v, 16, 64);
        v += __shfl_xor(v, 32, 64);
        if (q == 0) ksq_red[w][16 * t4 + l15] = v;
    }
    __syncthreads();
    if (tid < 64)
        ksq_part[(size_t)(b * G1 + g) * 64 + tid] =
            ksq_red[0][tid] + ksq_red[1][tid] + ksq_red[2][tid] + ksq_red[3][tid];
}

// ---------------- K2: reduce partials over g; kvw_t[b][d][c] = bf16(inv_k[c]*sum_e kvu[c][e]*w_ln[d][e])
__global__ void k2_kvw(const float* __restrict__ kvu_part, const float* __restrict__ ksq_part,
                       const float* __restrict__ w_ln, u16* __restrict__ kvw_t) {
    __shared__ float wln_s[64 * 68];
    __shared__ float kvr[16 * 68];
    __shared__ float inv_k[16];
    const int tid = threadIdx.x;
    const int c0 = blockIdx.x * 16, b = blockIdx.y;
    for (int idx = tid; idx < 4096; idx += 256) {
        int d = idx >> 6, e = idx & 63;
        wln_s[d * 68 + e] = w_ln[idx];
    }
    #pragma unroll
    for (int l = 0; l < 4; ++l) {
        int idx = tid + 256 * l;
        int cl = idx >> 6, e = idx & 63;
        float s = 0.f;
        for (int g = 0; g < G1; ++g)
            s += kvu_part[(size_t)(b * G1 + g) * 4096 + (c0 + cl) * 64 + e];
        kvr[cl * 68 + e] = s;
    }
    if (tid < 16) {
        float s = 0.f;
        for (int g = 0; g < G1; ++g)
            s += ksq_part[(size_t)(b * G1 + g) * 64 + c0 + tid];
        inv_k[tid] = 1.f / (fmaxf(sqrtf(s), 1e-12f) * 256.f);
    }
    __syncthreads();
    #pragma unroll
    for (int l = 0; l < 4; ++l) {
        int idx = tid + 256 * l;
        int d = idx >> 4, cl = idx & 15;
        float s = 0.f;
        #pragma unroll 8
        for (int e = 0; e < 64; ++e)
            s += kvr[cl * 68 + e] * wln_s[d * 68 + e];
        kvw_t[(size_t)b * 4096 + d * 64 + c0 + cl] = f2bf(s * inv_k[cl]);
    }
}

// ---------------- K3: per n-tile of 64: MFMA q|o GEMM; q stats; q2@kvw MFMA; transposed store
__global__ __launch_bounds__(256) void k3_out(const float* __restrict__ x,
        const u16* __restrict__ w_q_bf, const u16* __restrict__ wvln_bf,
        const float* __restrict__ b_qkv, const float* __restrict__ bias2,
        const u16* __restrict__ kvw_t, float* __restrict__ out) {
    __shared__ u16 qt[64 * STK];    // q2^T-ish: [n][c] bf16 (A-operand for GEMM B)
    __shared__ float ot[64 * STO];  // [d][n] fp32 for coalesced store
    const int tid = threadIdx.x;
    const int w = tid >> 6, lane = tid & 63, q = lane >> 4, l15 = lane & 15;
    const int b = blockIdx.y;
    const int n0 = blockIdx.x * 64;
    const float* xb = x + (size_t)b * 64 * NN;

    float bias[8];
    #pragma unroll
    for (int t8 = 0; t8 < 4; ++t8) bias[t8] = b_qkv[16 * t8 + l15];
    #pragma unroll
    for (int t8 = 4; t8 < 8; ++t8) bias[t8] = bias2[16 * (t8 - 4) + l15];

    // ---- GEMM A: cols 0..63 = q, 64..127 = x@wvln^T (+bias2)
    f32x4_t accA[8];
    #pragma unroll
    for (int t8 = 0; t8 < 8; ++t8)
        accA[t8] = (f32x4_t){bias[t8], bias[t8], bias[t8], bias[t8]};
    #pragma unroll
    for (int ks = 0; ks < 2; ++ks) {
        const float* xp = xb + (size_t)(ks * 32 + q * 8) * NN + n0 + 16 * w + l15;
        union { u16 u[8]; bf16x8_t v; } af;
        #pragma unroll
        for (int j = 0; j < 8; ++j) af.u[j] = f2bf(xp[(size_t)j * NN]);
        #pragma unroll
        for (int t8 = 0; t8 < 8; ++t8) {
            const u16* wp = (t8 < 4) ? (w_q_bf + (16 * t8 + l15) * 64)
                                     : (wvln_bf + (16 * (t8 - 4) + l15) * 64);
            bf16x8_t bf = *(const bf16x8_t*)(wp + ks * 32 + q * 8);
            accA[t8] = __builtin_amdgcn_mfma_f32_16x16x32_bf16(af.v, bf, accA[t8], 0, 0, 0);
        }
    }
    // ---- q stats: mu, q2s; q2; w_row = 1/max(||q2||, 1e-12*(q2s+eps))
    float mu[4], q2s[4];
    #pragma unroll
    for (int r = 0; r < 4; ++r) {
        float a0 = accA[0][r], a1 = accA[1][r], a2 = accA[2][r], a3 = accA[3][r];
        float s1 = a0 + a1 + a2 + a3;
        float s2 = a0 * a0 + a1 * a1 + a2 * a2 + a3 * a3;
        #pragma unroll
        for (int m = 1; m <= 8; m <<= 1) {
            s1 += __shfl_xor(s1, m, 64);
            s2 += __shfl_xor(s2, m, 64);
        }
        mu[r] = s1 * 0.015625f;
        q2s[r] = s2 - 64.f * mu[r] * mu[r];
    }
    float q2v[4][4];
    float s4[4] = {0.f, 0.f, 0.f, 0.f};
    #pragma unroll
    for (int t4 = 0; t4 < 4; ++t4)
        #pragma unroll
        for (int r = 0; r < 4; ++r) {
            float d = accA[t4][r] - mu[r];
            float v2 = d * d;
            q2v[t4][r] = v2;
            s4[r] += v2 * v2;
        }
    float w_row[4];
    #pragma unroll
    for (int r = 0; r < 4; ++r) {
        float s = s4[r];
        #pragma unroll
        for (int m = 1; m <= 8; m <<= 1) s += __shfl_xor(s, m, 64);
        w_row[r] = 1.f / fmaxf(sqrtf(s), 1e-12f * (q2s[r] + 1e-7f));
    }
    // ---- q2 -> qt LDS ([n][c] bf16)
    #pragma unroll
    for (int t4 = 0; t4 < 4; ++t4)
        #pragma unroll
        for (int r = 0; r < 4; ++r)
            qt[(16 * w + 4 * q + r) * STK + 16 * t4 + l15] = f2bf(q2v[t4][r]);
    __syncthreads();
    // ---- GEMM B: t2[n][d] = sum_c q2[n][c]*kvw[c][d]
    f32x4_t accB[4];
    #pragma unroll
    for (int dt = 0; dt < 4; ++dt) accB[dt] = (f32x4_t){0.f, 0.f, 0.f, 0.f};
    #pragma unroll
    for (int ks = 0; ks < 2; ++ks) {
        union { bf16x8_t v; uint2 h[2]; } a2;
        const u16* ap = &qt[(16 * w + l15) * STK + ks * 32 + q * 8];
        a2.h[0] = *(const uint2*)ap;
        a2.h[1] = *(const uint2*)(ap + 4);
        #pragma unroll
        for (int dt = 0; dt < 4; ++dt) {
            bf16x8_t bf = *(const bf16x8_t*)(kvw_t + (size_t)b * 4096 + (16 * dt + l15) * 64 + ks * 32 + q * 8);
            accB[dt] = __builtin_amdgcn_mfma_f32_16x16x32_bf16(a2.v, bf, accB[dt], 0, 0, 0);
        }
    }
    // ---- epilogue: out = o + w_row * t2 ; transpose through LDS
    #pragma unroll
    for (int dt = 0; dt < 4; ++dt) {
        #pragma unroll
        for (int rp = 0; rp < 2; ++rp) {
            float o0 = accA[4 + dt][2 * rp] + w_row[2 * rp] * accB[dt][2 * rp];
            float o1 = accA[4 + dt][2 * rp + 1] + w_row[2 * rp + 1] * accB[dt][2 * rp + 1];
            *(float2*)&ot[(16 * dt + l15) * STO + 16 * w + 4 * q + 2 * rp] = make_float2(o0, o1);
        }
    }
    __syncthreads();
    #pragma unroll
    for (int l = 0; l < 4; ++l) {
        int idx = tid + 256 * l;
        int d = idx >> 4, ng = idx & 15;
        *(float4*)(out + ((size_t)(b * 64 + d)) * NN + n0 + 4 * ng) = *(const float4*)&ot[d * STO + 4 * ng];
    }
}

extern "C" void kernel_launch(void* const* d_in, const int* in_sizes, int n_in,
                              void* d_out, int out_size, void* d_ws, size_t ws_size,
                              hipStream_t stream) {
    const float* x     = (const float*)d_in[0];
    const float* w_qkv = (const float*)d_in[1];
    const float* b_qkv = (const float*)d_in[2];
    const float* w_ln  = (const float*)d_in[3];
    const float* b_ln  = (const float*)d_in[4];
    float* out = (float*)d_out;
    char* ws = (char*)d_ws;
    // byte layout (total 12.88 MB, under round-0's 12.93 MB footprint)
    float* kvu_part = (float*)(ws);                       // 8*96*4096 f32
    float* ksq_part = (float*)(ws + 12582912);            // 8*96*64 f32
    u16*   kvw_t    = (u16*)  (ws + 12779520);            // 8*4096 bf16
    u16*   w_kv_bf  = (u16*)  (ws + 12845056);            // 128*64 bf16
    u16*   w_q_bf   = (u16*)  (ws + 12861440);            // 64*64 bf16
    u16*   wvln_bf  = (u16*)  (ws + 12869632);            // 64*64 bf16
    float* bias2    = (float*)(ws + 12877824);            // 64 f32

    k0_prep<<<dim3(65), dim3(256), 0, stream>>>(w_qkv, b_qkv, w_ln, b_ln,
                                                w_kv_bf, w_q_bf, wvln_bf, bias2);
    k1_kv<<<dim3(G1, 8), dim3(256), 0, stream>>>(x, w_kv_bf, b_qkv, kvu_part, ksq_part);
    k2_kvw<<<dim3(4, 8), dim3(256), 0, stream>>>(kvu_part, ksq_part, w_ln, kvw_t);
    k3_out<<<dim3(1024, 8), dim3(256), 0, stream>>>(x, w_q_bf, wvln_bf, b_qkv, bias2, kvw_t, out);
}